// Round 2
// baseline (110.500 us; speedup 1.0000x reference)
//
#include <hip/hip_runtime.h>
#include <cstdint>

#define S_LEN  8192
#define IN_DIM 512
#define D_DIM  64
#define BATCH  2
#define ROWS   (BATCH * S_LEN)   // 16384
#define NTOT   192               // 3 * 64 concat W rows

typedef unsigned short u16;
typedef unsigned int   u32;
typedef __attribute__((ext_vector_type(8))) short          s8v;   // 8 bf16 bits
typedef __attribute__((ext_vector_type(8))) unsigned short us8;
typedef __attribute__((ext_vector_type(4))) float          f4v;

// ---- ws layout (float offsets) ----
#define OFF_Y1  0
#define OFF_Y2  (ROWS * D_DIM)                     // 1048576
#define OFF_Y3  (2 * ROWS * D_DIM)                 // 2097152
#define OFF_M   (3 * ROWS * D_DIM)                 // 3145728  [B][64][64]
#define OFF_U   (OFF_M + BATCH * D_DIM * D_DIM)
#define OFF_V   (OFF_U + BATCH * D_DIM)
#define OFF_BO2 (OFF_V + BATCH * D_DIM)            // [B][512]
#define OFF_W16 (OFF_BO2 + BATCH * IN_DIM)         // start of ushort region
// ushort offsets inside region at (u16*)(ws + OFF_W16):
#define U_WHI   0        // [192][512]
#define U_WLO   98304    // [192][512]
#define U_N2THI 0        // [B][512][64]  (overlaps WHI -- W dead after k_proj)
#define U_N2TLO 65536    // [B][512][64]
// total ushort region = 196608 u16 = 98304 floats -> ws = 3,253,504 floats (13.0 MB)

__device__ __forceinline__ u16 f2bf(float f) {
    u32 u = __float_as_uint(f);
    return (u16)((u + 0x7fffu + ((u >> 16) & 1u)) >> 16);   // RNE
}
__device__ __forceinline__ float bf2f(u16 h) {
    return __uint_as_float(((u32)h) << 16);
}
#define MFMA(a, b, c) __builtin_amdgcn_mfma_f32_16x16x32_bf16((a), (b), (c), 0, 0, 0)

// ---------------------------------------------------------------------------
// k_split: W{1,2,3} -> concat bf16 hi/lo [192][512]; also zero M/u/v accumulators.
// grid 96 x 256, thread handles 4 elems.
// ---------------------------------------------------------------------------
__global__ __launch_bounds__(256) void k_split(
    const float* __restrict__ W1, const float* __restrict__ W2,
    const float* __restrict__ W3, float* __restrict__ ws)
{
    const int gid = blockIdx.x * 256 + threadIdx.x;    // 0..24575
    if (gid < BATCH * D_DIM * D_DIM + 2 * BATCH * D_DIM)   // 8448
        ws[OFF_M + gid] = 0.f;
    const int w   = gid >> 13;                 // 8192 gids per W
    const int off = (gid & 8191) * 4;          // elem offset inside one W
    const float* Wsrc = (w == 0) ? W1 : (w == 1) ? W2 : W3;
    float4 v = *(const float4*)(Wsrc + off);
    u16* WHI = (u16*)(ws + OFF_W16) + U_WHI + gid * 4;
    u16* WLO = (u16*)(ws + OFF_W16) + U_WLO + gid * 4;
    ushort4 h, l;
    h.x = f2bf(v.x); h.y = f2bf(v.y); h.z = f2bf(v.z); h.w = f2bf(v.w);
    l.x = f2bf(v.x - bf2f(h.x)); l.y = f2bf(v.y - bf2f(h.y));
    l.z = f2bf(v.z - bf2f(h.z)); l.w = f2bf(v.w - bf2f(h.w));
    *(ushort4*)WHI = h;
    *(ushort4*)WLO = l;
}

// ---------------------------------------------------------------------------
// k_proj: Y[16384][192] = x @ Wcat^T via split-bf16 MFMA (hh+hl+lh).
// Block = 128 thr (2 waves), BM=32 rows; wave = 16 rows x 192 cols (12 tiles).
// x converted fp32->hi/lo bf16 into XOR-swizzled LDS; W frags direct from L2.
// grid 512.
// ---------------------------------------------------------------------------
__global__ __launch_bounds__(128) void k_proj(
    const float* __restrict__ x, float* __restrict__ ws)
{
    const u16* WHI = (const u16*)(ws + OFF_W16) + U_WHI;
    const u16* WLO = (const u16*)(ws + OFF_W16) + U_WLO;

    __shared__ u16 xhi[32 * 64];
    __shared__ u16 xlo[32 * 64];

    const int tid  = threadIdx.x;
    const int lane = tid & 63;
    const int wid  = tid >> 6;        // 0..1
    const int ln   = lane & 15;
    const int hf   = lane >> 4;       // 0..3
    const int row0 = blockIdx.x * 32;

    // staging map: thread t -> row = t>>2 (0..31), k0 = (t&3)*16 (16 floats)
    const int srow = tid >> 2;
    const int sk   = (tid & 3) * 16;
    const float* xsrc = x + (size_t)(row0 + srow) * IN_DIM + sk;

    f4v acc[12];
#pragma unroll
    for (int t = 0; t < 12; ++t) acc[t] = (f4v)0.f;

    float4 pf[4];
#pragma unroll
    for (int q = 0; q < 4; ++q) pf[q] = *(const float4*)(xsrc + q * 4);

    for (int c = 0; c < 8; ++c) {
        // convert 16 floats -> hi/lo, write swizzled (2x b128 each)
        {
            float vv[16];
#pragma unroll
            for (int q = 0; q < 4; ++q) {
                vv[q * 4 + 0] = pf[q].x; vv[q * 4 + 1] = pf[q].y;
                vv[q * 4 + 2] = pf[q].z; vv[q * 4 + 3] = pf[q].w;
            }
            u16 h[16], l[16];
#pragma unroll
            for (int q = 0; q < 16; ++q) {
                h[q] = f2bf(vv[q]);
                l[q] = f2bf(vv[q] - bf2f(h[q]));
            }
            const int rbase = srow * 64;
            const int sw = srow & 7;
#pragma unroll
            for (int g = 0; g < 2; ++g) {
                const int slot = (((sk >> 3) + g) ^ sw) << 3;
                us8 vh, vl;
#pragma unroll
                for (int q = 0; q < 8; ++q) { vh[q] = h[g * 8 + q]; vl[q] = l[g * 8 + q]; }
                *(us8*)(xhi + rbase + slot) = vh;
                *(us8*)(xlo + rbase + slot) = vl;
            }
        }
        __syncthreads();
        if (c < 7) {
            const float* nx = xsrc + (c + 1) * 64;
#pragma unroll
            for (int q = 0; q < 4; ++q) pf[q] = *(const float4*)(nx + q * 4);
        }
        // compute: 2 ksteps over this 64-wide chunk
#pragma unroll
        for (int ks = 0; ks < 2; ++ks) {
            const int kk   = ks * 32 + hf * 8;              // 0..63 within chunk
            const int arow = wid * 16 + ln;
            const int slot = (((kk >> 3) ^ (arow & 7)) << 3);
            s8v ahi = *(const s8v*)(xhi + arow * 64 + slot);
            s8v alo = *(const s8v*)(xlo + arow * 64 + slot);
            const int wkk = c * 64 + ks * 32 + hf * 8;      // global k
            const u16* bh = WHI + ln * IN_DIM + wkk;
            const u16* bl = WLO + ln * IN_DIM + wkk;
#pragma unroll
            for (int ct = 0; ct < 12; ++ct) {
                s8v bhi = *(const s8v*)(bh + ct * 16 * IN_DIM);
                s8v blo = *(const s8v*)(bl + ct * 16 * IN_DIM);
                acc[ct] = MFMA(ahi, bhi, acc[ct]);
                acc[ct] = MFMA(ahi, blo, acc[ct]);
                acc[ct] = MFMA(alo, bhi, acc[ct]);
            }
        }
        __syncthreads();
    }

    // epilogue: C layout row=(l>>4)*4+r (A side), col=l&15 (B side)
#pragma unroll
    for (int ct = 0; ct < 12; ++ct) {
        const int w  = ct >> 2;
        const int cc = (ct & 3) * 16 + ln;
        float* Y = ws + ((w == 0) ? OFF_Y1 : (w == 1) ? OFF_Y2 : OFF_Y3);
        const int rr = row0 + wid * 16 + hf * 4;
#pragma unroll
        for (int r = 0; r < 4; ++r)
            Y[(size_t)(rr + r) * D_DIM + cc] = acc[ct][r];
    }
}

// ---------------------------------------------------------------------------
// k_M: M[b] += Y2^T @ Y3 (fp32 VALU, small); u/v colsums. Unchanged from r0.
// ---------------------------------------------------------------------------
__global__ __launch_bounds__(256) void k_M(float* __restrict__ ws)
{
    const int split = blockIdx.x;
    const int b     = blockIdx.y;
    const float* Y2 = ws + OFF_Y2 + (size_t)b * S_LEN * D_DIM;
    const float* Y3 = ws + OFF_Y3 + (size_t)b * S_LEN * D_DIM;

    __shared__ float Y2s[64][68];
    __shared__ float Y3s[64][68];

    const int tid = threadIdx.x;
    const int tr = tid >> 4, tc = tid & 15;

    float acc[4][4];
#pragma unroll
    for (int i = 0; i < 4; ++i)
#pragma unroll
        for (int j = 0; j < 4; ++j) acc[i][j] = 0.f;
    float uacc = 0.f, vacc = 0.f;

    for (int sub = 0; sub < 2; ++sub) {
        const int row0 = split * 128 + sub * 64;
#pragma unroll
        for (int t = 0; t < 4; ++t) {
            int idx = tid + t * 256;
            int r   = idx >> 4;
            int c4  = idx & 15;
            *(float4*)&Y2s[r][c4 * 4] = *(const float4*)(Y2 + (size_t)(row0 + r) * D_DIM + c4 * 4);
            *(float4*)&Y3s[r][c4 * 4] = *(const float4*)(Y3 + (size_t)(row0 + r) * D_DIM + c4 * 4);
        }
        __syncthreads();
#pragma unroll 8
        for (int r = 0; r < 64; ++r) {
            float4 a  = *(const float4*)&Y2s[r][tr * 4];
            float4 bv = *(const float4*)&Y3s[r][tc * 4];
            float av[4] = {a.x, a.y, a.z, a.w};
            float bw[4] = {bv.x, bv.y, bv.z, bv.w};
#pragma unroll
            for (int i = 0; i < 4; ++i)
#pragma unroll
                for (int j = 0; j < 4; ++j) acc[i][j] += av[i] * bw[j];
        }
        if (tid < 64) {
#pragma unroll 16
            for (int r = 0; r < 64; ++r) uacc += Y2s[r][tid];
        } else if (tid < 128) {
#pragma unroll 16
            for (int r = 0; r < 64; ++r) vacc += Y3s[r][tid - 64];
        }
        __syncthreads();
    }

    float* M = ws + OFF_M + b * D_DIM * D_DIM;
#pragma unroll
    for (int i = 0; i < 4; ++i)
#pragma unroll
        for (int j = 0; j < 4; ++j)
            atomicAdd(&M[(tr * 4 + i) * D_DIM + tc * 4 + j], acc[i][j]);
    if (tid < 64)       atomicAdd(ws + OFF_U + b * D_DIM + tid, uacc);
    else if (tid < 128) atomicAdd(ws + OFF_V + b * D_DIM + tid - 64, vacc);
}

// ---------------------------------------------------------------------------
// k_N2: finalize M (bias cross-terms), N2 = M @ WO^T; write N2^T as bf16 hi/lo
// [B][512][64]; also bO2 = bO + b1^T N2.  grid (8, B), 256 thr.
// ---------------------------------------------------------------------------
__global__ __launch_bounds__(256) void k_N2(
    const float* __restrict__ b1, const float* __restrict__ b2,
    const float* __restrict__ b3, const float* __restrict__ WO,
    const float* __restrict__ bO, float* __restrict__ ws)
{
    const int jb = blockIdx.x;
    const int b  = blockIdx.y;

    __shared__ float Ms[64][68];
    __shared__ float WOs[64][68];
    __shared__ float us[64], vs[64];
    __shared__ float bo2s[64];

    const int tid = threadIdx.x;
    const float* M = ws + OFF_M + b * D_DIM * D_DIM;
#pragma unroll
    for (int t = 0; t < 16; ++t) {
        int e = t * 256 + tid;
        Ms[e >> 6][e & 63] = M[e];
    }
    if (tid < 64)       us[tid]      = ws[OFF_U + b * D_DIM + tid];
    else if (tid < 128) vs[tid - 64] = ws[OFF_V + b * D_DIM + tid - 64];
    if (tid < 64) bo2s[tid] = 0.f;
    __syncthreads();
#pragma unroll
    for (int t = 0; t < 16; ++t) {
        int e = t * 256 + tid;
        int d2 = e >> 6, d3 = e & 63;
        Ms[d2][d3] += us[d2] * b3[d3] + b2[d2] * vs[d3] + (float)S_LEN * b2[d2] * b3[d3];
    }
    const int j0 = jb * 64;
#pragma unroll
    for (int t = 0; t < 4; ++t) {
        int idx = tid + t * 256;
        int r = idx >> 4, c4 = idx & 15;
        *(float4*)&WOs[r][c4 * 4] = *(const float4*)(WO + (size_t)(j0 + r) * D_DIM + c4 * 4);
    }
    __syncthreads();

    const int tr = tid >> 4, tc = tid & 15;
    float acc[4][4];
#pragma unroll
    for (int i = 0; i < 4; ++i)
#pragma unroll
        for (int j = 0; j < 4; ++j) acc[i][j] = 0.f;
#pragma unroll 8
    for (int d = 0; d < 64; ++d) {
        float av[4], bw[4];
#pragma unroll
        for (int i = 0; i < 4; ++i) av[i] = Ms[tr * 4 + i][d];
#pragma unroll
        for (int j = 0; j < 4; ++j) bw[j] = WOs[tc * 4 + j][d];
#pragma unroll
        for (int i = 0; i < 4; ++i)
#pragma unroll
            for (int j = 0; j < 4; ++j) acc[i][j] += av[i] * bw[j];
    }
    // write N2^T hi/lo: N2T[col][d], col = j0+tc*4+j, d = tr*4+i
    u16* N2THI = (u16*)(ws + OFF_W16) + U_N2THI + b * IN_DIM * D_DIM;
    u16* N2TLO = (u16*)(ws + OFF_W16) + U_N2TLO + b * IN_DIM * D_DIM;
#pragma unroll
    for (int i = 0; i < 4; ++i)
#pragma unroll
        for (int j = 0; j < 4; ++j) {
            const int col = j0 + tc * 4 + j;
            const int d   = tr * 4 + i;
            float val = acc[i][j];
            u16 h = f2bf(val);
            N2THI[col * D_DIM + d] = h;
            N2TLO[col * D_DIM + d] = f2bf(val - bf2f(h));
        }
    // bias: bo2s[col-j0] += sum_d b1[d] * N2[d][col]
#pragma unroll
    for (int j = 0; j < 4; ++j) {
        float s = 0.f;
#pragma unroll
        for (int i = 0; i < 4; ++i) s += b1[tr * 4 + i] * acc[i][j];
        atomicAdd(&bo2s[tc * 4 + j], s);
    }
    __syncthreads();
    if (tid < 64)
        ws[OFF_BO2 + b * IN_DIM + j0 + tid] = bO[j0 + tid] + bo2s[tid];
}

// ---------------------------------------------------------------------------
// k_out: out = sigmoid(Y1 @ N2 + bO2) via split-bf16 MFMA.
// Block 256 thr (4 waves), BM=32; wave = 2 rowtiles x 8 coltiles (128 cols).
// grid 512.
// ---------------------------------------------------------------------------
__global__ __launch_bounds__(256) void k_out(
    const float* __restrict__ ws, float* __restrict__ out)
{
    const int row0 = blockIdx.x * 32;
    const int b    = row0 >> 13;
    const u16* N2THI = (const u16*)(ws + OFF_W16) + U_N2THI + b * IN_DIM * D_DIM;
    const u16* N2TLO = (const u16*)(ws + OFF_W16) + U_N2TLO + b * IN_DIM * D_DIM;

    __shared__ u16 yhi[32 * 64];
    __shared__ u16 ylo[32 * 64];

    const int tid  = threadIdx.x;
    const int lane = tid & 63;
    const int wid  = tid >> 6;       // 0..3
    const int ln   = lane & 15;
    const int hf   = lane >> 4;

    // stage Y1 tile [32][64] -> hi/lo swizzled LDS
    {
        const int srow = tid >> 3;          // 0..31
        const int sk   = (tid & 7) * 8;     // 0..56
        const float* ysrc = ws + OFF_Y1 + (size_t)(row0 + srow) * D_DIM + sk;
        float4 a = *(const float4*)(ysrc);
        float4 c = *(const float4*)(ysrc + 4);
        float vv[8] = {a.x, a.y, a.z, a.w, c.x, c.y, c.z, c.w};
        us8 vh, vl;
#pragma unroll
        for (int q = 0; q < 8; ++q) {
            u16 h = f2bf(vv[q]);
            vh[q] = h;
            vl[q] = f2bf(vv[q] - bf2f(h));
        }
        const int slot = (((sk >> 3) ^ (srow & 7)) << 3);
        *(us8*)(yhi + srow * 64 + slot) = vh;
        *(us8*)(ylo + srow * 64 + slot) = vl;
    }
    __syncthreads();

    f4v acc[16];
#pragma unroll
    for (int t = 0; t < 16; ++t) acc[t] = (f4v)0.f;

    const int colbase = wid * 128;
#pragma unroll
    for (int ks = 0; ks < 2; ++ks) {
        const int kk = ks * 32 + hf * 8;
        s8v ah[2], al[2];
#pragma unroll
        for (int rt = 0; rt < 2; ++rt) {
            const int arow = rt * 16 + ln;
            const int slot = (((kk >> 3) ^ (arow & 7)) << 3);
            ah[rt] = *(const s8v*)(yhi + arow * 64 + slot);
            al[rt] = *(const s8v*)(ylo + arow * 64 + slot);
        }
#pragma unroll
        for (int ct = 0; ct < 8; ++ct) {
            const int col = colbase + ct * 16 + ln;
            s8v bh = *(const s8v*)(N2THI + col * D_DIM + kk);
            s8v bl = *(const s8v*)(N2TLO + col * D_DIM + kk);
#pragma unroll
            for (int rt = 0; rt < 2; ++rt) {
                acc[rt * 8 + ct] = MFMA(ah[rt], bh, acc[rt * 8 + ct]);
                acc[rt * 8 + ct] = MFMA(ah[rt], bl, acc[rt * 8 + ct]);
                acc[rt * 8 + ct] = MFMA(al[rt], bh, acc[rt * 8 + ct]);
            }
        }
    }

    const float* bO2 = ws + OFF_BO2 + b * IN_DIM;
#pragma unroll
    for (int ct = 0; ct < 8; ++ct) {
        const int col = colbase + ct * 16 + ln;
        const float bias = bO2[col];
#pragma unroll
        for (int rt = 0; rt < 2; ++rt) {
            const int rr = row0 + rt * 16 + hf * 4;
            f4v a = acc[rt * 8 + ct];
#pragma unroll
            for (int r = 0; r < 4; ++r) {
                float p = a[r] + bias;
                out[(size_t)(rr + r) * IN_DIM + col] =
                    __builtin_amdgcn_rcpf(1.f + __expf(-p));
            }
        }
    }
}

// ---------------------------------------------------------------------------
extern "C" void kernel_launch(void* const* d_in, const int* in_sizes, int n_in,
                              void* d_out, int out_size, void* d_ws, size_t ws_size,
                              hipStream_t stream)
{
    const float* x  = (const float*)d_in[0];
    const float* W1 = (const float*)d_in[1];
    const float* b1 = (const float*)d_in[2];
    const float* W2 = (const float*)d_in[3];
    const float* b2 = (const float*)d_in[4];
    const float* W3 = (const float*)d_in[5];
    const float* b3 = (const float*)d_in[6];
    const float* WO = (const float*)d_in[7];
    const float* bO = (const float*)d_in[8];
    float* out = (float*)d_out;
    float* ws  = (float*)d_ws;

    k_split<<<96,              256, 0, stream>>>(W1, W2, W3, ws);
    k_proj <<<512,             128, 0, stream>>>(x, ws);
    k_M    <<<dim3(64, BATCH), 256, 0, stream>>>(ws);
    k_N2   <<<dim3(8, BATCH),  256, 0, stream>>>(b1, b2, b3, WO, bO, ws);
    k_out  <<<512,             256, 0, stream>>>(ws, out);
}

// Round 3
// 68.454 us; speedup vs baseline: 1.6142x; 1.6142x over previous
//
#include <hip/hip_runtime.h>
#include <cstdint>

#define S_LEN  8192
#define IN_DIM 512
#define D_DIM  64
#define BATCH  2
#define ROWS   (BATCH * S_LEN)   // 16384

typedef unsigned short u16;
typedef unsigned int   u32;
typedef __attribute__((ext_vector_type(8))) short          s8v;   // 8 bf16 (4 VGPR)
typedef __attribute__((ext_vector_type(4))) float          f4v;

// ---- ws layout (float offsets) ----
#define MP_STRIDE 4224                         // 4096 M cells + 64 u + 64 v
#define OFF_MP   0                             // [256][4224] fp32 partials
#define OFF_M    1081344                       // [B][4096]
#define OFF_U    1089536                       // [B][64]
#define OFF_V    1089664                       // [B][64]
#define OFF_BO2  1089792                       // [B][512]
#define OFF_U16  1090816                       // u16 region starts here
// u16 offsets within region:
#define U_WHI    0                             // [192][512]
#define U_WLO    98304                         // [192][512]
#define U_N2THI  0                             // [B][512][64] (reuse; W dead)
#define U_N2TLO  65536
#define U_Y1HI   196608                        // [16384][64]
#define U_Y1LO   1245184                       // [16384][64]
// total = 2,237,696 floats = 8.95 MB

__device__ __forceinline__ u16 f2bf_rne(float f) {
    u32 u = __float_as_uint(f);
    return (u16)((u + 0x7fffu + ((u >> 16) & 1u)) >> 16);
}
__device__ __forceinline__ float bf2f(u32 h) {
    return __uint_as_float(h << 16);
}
__device__ __forceinline__ float hi_trunc(float f) {
    return __uint_as_float(__float_as_uint(f) & 0xFFFF0000u);
}
// pack top-16 bits of f0 (low half) and f1 (high half) into one u32
__device__ __forceinline__ u32 packhi2(float f0, float f1) {
    return __builtin_amdgcn_perm(__float_as_uint(f1), __float_as_uint(f0), 0x07060302u);
}
#define MFMA(a, b, c) __builtin_amdgcn_mfma_f32_16x16x32_bf16((a), (b), (c), 0, 0, 0)

// ---------------------------------------------------------------------------
// k_split: W{1,2,3} -> concat bf16 hi/lo [192][512] (RNE, one-time).
// ---------------------------------------------------------------------------
__global__ __launch_bounds__(256) void k_split(
    const float* __restrict__ W1, const float* __restrict__ W2,
    const float* __restrict__ W3, float* __restrict__ ws)
{
    const int gid = blockIdx.x * 256 + threadIdx.x;    // 0..24575
    const int w   = gid >> 13;
    const int off = (gid & 8191) * 4;
    const float* Wsrc = (w == 0) ? W1 : (w == 1) ? W2 : W3;
    float4 v = *(const float4*)(Wsrc + off);
    u16* WHI = (u16*)(ws + OFF_U16) + U_WHI + gid * 4;
    u16* WLO = (u16*)(ws + OFF_U16) + U_WLO + gid * 4;
    ushort4 h, l;
    h.x = f2bf_rne(v.x); h.y = f2bf_rne(v.y); h.z = f2bf_rne(v.z); h.w = f2bf_rne(v.w);
    l.x = f2bf_rne(v.x - bf2f(h.x)); l.y = f2bf_rne(v.y - bf2f(h.y));
    l.z = f2bf_rne(v.z - bf2f(h.z)); l.w = f2bf_rne(v.w - bf2f(h.w));
    *(ushort4*)WHI = h;
    *(ushort4*)WLO = l;
}

// ---------------------------------------------------------------------------
// k_proj: Y[16384][192] = x @ Wcat^T (split-bf16 MFMA, hh+hl+lh), fused with
//   per-block M-partial = Y2_tile^T @ Y3_tile and u/v colsum partials.
// Block 256 thr = 4 waves; BM=64 rows; wave g = cols [48g,48g+48) (R=4,C=3).
// B double-buffered in regs, prefetched 1 k-step ahead. grid 256.
// ---------------------------------------------------------------------------
__global__ __launch_bounds__(256, 1) void k_proj(
    const float* __restrict__ x, float* __restrict__ ws)
{
    u16* const ub = (u16*)(ws + OFF_U16);
    const u16* WHI = ub + U_WHI;
    const u16* WLO = ub + U_WLO;
    u16* Y1HI = ub + U_Y1HI;
    u16* Y1LO = ub + U_Y1LO;

    // union LDS: main loop uses [0..8192) as swizzled xhi/xlo [64][64];
    // epilogue uses 6 x [64][72] u16 transpose buffers (Y1/Y2/Y3 hi,lo).
    __shared__ u16 lds[6 * 64 * 72];   // 27648 u16 = 54 KB
    u16* xhi = lds;
    u16* xlo = lds + 4096;

    const int tid  = threadIdx.x;
    const int lane = tid & 63;
    const int g    = tid >> 6;        // wave id = colgroup 0..3
    const int ln   = lane & 15;
    const int hf   = lane >> 4;       // 0..3
    const int row0 = blockIdx.x * 64;

    // staging map: thread -> (srow 0..63, sk in {0,16,32,48})
    const int srow = tid >> 2;
    const int sk   = (tid & 3) * 16;
    const float* xsrc = x + (size_t)(row0 + srow) * IN_DIM + sk;

    f4v acc[4][3];
#pragma unroll
    for (int rt = 0; rt < 4; ++rt)
#pragma unroll
        for (int ct = 0; ct < 3; ++ct) acc[rt][ct] = (f4v)0.f;

    const u16* bh = WHI + (size_t)(g * 48 + ln) * IN_DIM;
    const u16* bl = WLO + (size_t)(g * 48 + ln) * IN_DIM;

    s8v Bh0[3], Bl0[3], Bh1[3], Bl1[3];
#pragma unroll
    for (int ct = 0; ct < 3; ++ct) {          // t = 0
        Bh0[ct] = *(const s8v*)(bh + ct * 8192 + hf * 8);
        Bl0[ct] = *(const s8v*)(bl + ct * 8192 + hf * 8);
    }
    float4 pf[4];
#pragma unroll
    for (int q = 0; q < 4; ++q) pf[q] = *(const float4*)(xsrc + q * 4);

    for (int c = 0; c < 8; ++c) {
        // ---- stage x chunk: trunc hi/lo split, XOR-swizzled LDS ----
        {
            float vv[16];
#pragma unroll
            for (int q = 0; q < 4; ++q) {
                vv[q*4+0] = pf[q].x; vv[q*4+1] = pf[q].y;
                vv[q*4+2] = pf[q].z; vv[q*4+3] = pf[q].w;
            }
            const int rbase = srow * 64;
            const int sw = srow & 7;
#pragma unroll
            for (int gg = 0; gg < 2; ++gg) {
                const int e = gg * 8;
                uint4 H, L;
                H.x = packhi2(vv[e+0], vv[e+1]); H.y = packhi2(vv[e+2], vv[e+3]);
                H.z = packhi2(vv[e+4], vv[e+5]); H.w = packhi2(vv[e+6], vv[e+7]);
                float l0 = vv[e+0]-hi_trunc(vv[e+0]), l1 = vv[e+1]-hi_trunc(vv[e+1]);
                float l2 = vv[e+2]-hi_trunc(vv[e+2]), l3 = vv[e+3]-hi_trunc(vv[e+3]);
                float l4 = vv[e+4]-hi_trunc(vv[e+4]), l5 = vv[e+5]-hi_trunc(vv[e+5]);
                float l6 = vv[e+6]-hi_trunc(vv[e+6]), l7 = vv[e+7]-hi_trunc(vv[e+7]);
                L.x = packhi2(l0, l1); L.y = packhi2(l2, l3);
                L.z = packhi2(l4, l5); L.w = packhi2(l6, l7);
                const int slot = ((((sk >> 3) + gg) ^ sw) << 3);
                *(uint4*)(xhi + rbase + slot) = H;
                *(uint4*)(xlo + rbase + slot) = L;
            }
        }
        __syncthreads();
        if (c < 7) {
            const float* nx = xsrc + (c + 1) * 64;
#pragma unroll
            for (int q = 0; q < 4; ++q) pf[q] = *(const float4*)(nx + q * 4);
        }
        // ---- ks = 0: compute with buf0, prefetch t=2c+1 into buf1 ----
        {
            const int t1 = 2 * c + 1;
#pragma unroll
            for (int ct = 0; ct < 3; ++ct) {
                Bh1[ct] = *(const s8v*)(bh + ct * 8192 + t1 * 32 + hf * 8);
                Bl1[ct] = *(const s8v*)(bl + ct * 8192 + t1 * 32 + hf * 8);
            }
            s8v ah[4], al[4];
#pragma unroll
            for (int rt = 0; rt < 4; ++rt) {
                const int arow = rt * 16 + ln;
                const int slot = ((hf ^ (arow & 7)) << 3);
                ah[rt] = *(const s8v*)(xhi + arow * 64 + slot);
                al[rt] = *(const s8v*)(xlo + arow * 64 + slot);
            }
#pragma unroll
            for (int ct = 0; ct < 3; ++ct)
#pragma unroll
                for (int rt = 0; rt < 4; ++rt) {
                    acc[rt][ct] = MFMA(ah[rt], Bh0[ct], acc[rt][ct]);
                    acc[rt][ct] = MFMA(ah[rt], Bl0[ct], acc[rt][ct]);
                    acc[rt][ct] = MFMA(al[rt], Bh0[ct], acc[rt][ct]);
                }
        }
        // ---- ks = 1: compute with buf1, prefetch t=2c+2 into buf0 ----
        {
            if (c < 7) {
                const int t2 = 2 * c + 2;
#pragma unroll
                for (int ct = 0; ct < 3; ++ct) {
                    Bh0[ct] = *(const s8v*)(bh + ct * 8192 + t2 * 32 + hf * 8);
                    Bl0[ct] = *(const s8v*)(bl + ct * 8192 + t2 * 32 + hf * 8);
                }
            }
            s8v ah[4], al[4];
#pragma unroll
            for (int rt = 0; rt < 4; ++rt) {
                const int arow = rt * 16 + ln;
                const int slot = (((4 + hf) ^ (arow & 7)) << 3);
                ah[rt] = *(const s8v*)(xhi + arow * 64 + slot);
                al[rt] = *(const s8v*)(xlo + arow * 64 + slot);
            }
#pragma unroll
            for (int ct = 0; ct < 3; ++ct)
#pragma unroll
                for (int rt = 0; rt < 4; ++rt) {
                    acc[rt][ct] = MFMA(ah[rt], Bh1[ct], acc[rt][ct]);
                    acc[rt][ct] = MFMA(ah[rt], Bl1[ct], acc[rt][ct]);
                    acc[rt][ct] = MFMA(al[rt], Bh1[ct], acc[rt][ct]);
                }
        }
        __syncthreads();
    }

    // ================= epilogue =================
    // E1: write all acc tiles, trunc hi/lo split, into column-major LDS
    // transpose buffers YT[sel][c][r] (sel 0=Y1,1=Y2,2=Y3), stride 72.
#pragma unroll
    for (int rt = 0; rt < 4; ++rt) {
        const int rr = rt * 16 + hf * 4;
#pragma unroll
        for (int ct = 0; ct < 3; ++ct) {
            const int cg  = g * 48 + ct * 16 + ln;
            const int sel = cg >> 6;
            const int ci  = cg & 63;
            f4v a = acc[rt][ct];
            uint2 H, L;
            H.x = packhi2(a[0], a[1]); H.y = packhi2(a[2], a[3]);
            float l0 = a[0]-hi_trunc(a[0]), l1 = a[1]-hi_trunc(a[1]);
            float l2 = a[2]-hi_trunc(a[2]), l3 = a[3]-hi_trunc(a[3]);
            L.x = packhi2(l0, l1); L.y = packhi2(l2, l3);
            u16* dh = lds + (size_t)(sel * 2 + 0) * 4608 + ci * 72 + rr;
            u16* dl = lds + (size_t)(sel * 2 + 1) * 4608 + ci * 72 + rr;
            *(uint2*)dh = H;
            *(uint2*)dl = L;
        }
    }
    __syncthreads();

    // E3: M-partial = Y2^T @ Y3 over these 64 rows (wave g -> M rows 16g..16g+15)
    {
        const u16* y2h = lds + 2 * 4608;
        const u16* y2l = lds + 3 * 4608;
        const u16* y3h = lds + 4 * 4608;
        const u16* y3l = lds + 5 * 4608;
        f4v macc[4];
#pragma unroll
        for (int mj = 0; mj < 4; ++mj) macc[mj] = (f4v)0.f;
#pragma unroll
        for (int ks = 0; ks < 2; ++ks) {
            const int koff = ks * 32 + hf * 8;
            s8v a2h = *(const s8v*)(y2h + (g * 16 + ln) * 72 + koff);
            s8v a2l = *(const s8v*)(y2l + (g * 16 + ln) * 72 + koff);
#pragma unroll
            for (int mj = 0; mj < 4; ++mj) {
                s8v b3h = *(const s8v*)(y3h + (mj * 16 + ln) * 72 + koff);
                s8v b3l = *(const s8v*)(y3l + (mj * 16 + ln) * 72 + koff);
                macc[mj] = MFMA(a2h, b3h, macc[mj]);
                macc[mj] = MFMA(a2h, b3l, macc[mj]);
                macc[mj] = MFMA(a2l, b3h, macc[mj]);
            }
        }
        // E4: write M-partial
        float* mp = ws + OFF_MP + (size_t)blockIdx.x * MP_STRIDE;
#pragma unroll
        for (int mj = 0; mj < 4; ++mj)
#pragma unroll
            for (int r = 0; r < 4; ++r)
                mp[(g * 16 + hf * 4 + r) * 64 + mj * 16 + ln] = macc[mj][r];
    }

    // E2: store Y1 (cols 0..63) row-major bf16 hi/lo to global
    {
        const int r = tid >> 2;          // 0..63
        const int q = tid & 3;           // 16-col group
        u16 th[16], tl[16];
#pragma unroll
        for (int j = 0; j < 16; ++j) {
            const int ci = q * 16 + j;
            th[j] = lds[0 * 4608 + ci * 72 + r];
            tl[j] = lds[1 * 4608 + ci * 72 + r];
        }
        uint4 H, L;
        H.x = (u32)th[0] | ((u32)th[1] << 16);  H.y = (u32)th[2] | ((u32)th[3] << 16);
        H.z = (u32)th[4] | ((u32)th[5] << 16);  H.w = (u32)th[6] | ((u32)th[7] << 16);
        uint4 H2;
        H2.x = (u32)th[8] | ((u32)th[9] << 16);  H2.y = (u32)th[10] | ((u32)th[11] << 16);
        H2.z = (u32)th[12] | ((u32)th[13] << 16); H2.w = (u32)th[14] | ((u32)th[15] << 16);
        L.x = (u32)tl[0] | ((u32)tl[1] << 16);  L.y = (u32)tl[2] | ((u32)tl[3] << 16);
        L.z = (u32)tl[4] | ((u32)tl[5] << 16);  L.w = (u32)tl[6] | ((u32)tl[7] << 16);
        uint4 L2;
        L2.x = (u32)tl[8] | ((u32)tl[9] << 16);  L2.y = (u32)tl[10] | ((u32)tl[11] << 16);
        L2.z = (u32)tl[12] | ((u32)tl[13] << 16); L2.w = (u32)tl[14] | ((u32)tl[15] << 16);
        u16* dsth = Y1HI + (size_t)(row0 + r) * 64 + q * 16;
        u16* dstl = Y1LO + (size_t)(row0 + r) * 64 + q * 16;
        *(uint4*)(dsth)     = H;  *(uint4*)(dsth + 8) = H2;
        *(uint4*)(dstl)     = L;  *(uint4*)(dstl + 8) = L2;
    }

    // E5: u/v colsum partials (threads 0..127)
    if (tid < 128) {
        const int c = tid & 63;
        const u16* ph = lds + (size_t)((tid < 64) ? 2 : 4) * 4608 + c * 72;
        const u16* pl = lds + (size_t)((tid < 64) ? 3 : 5) * 4608 + c * 72;
        float s = 0.f;
#pragma unroll
        for (int q = 0; q < 16; ++q) {
            uint2 wh = *(const uint2*)(ph + q * 4);
            uint2 wl = *(const uint2*)(pl + q * 4);
            s += bf2f(wh.x & 0xFFFFu) + bf2f(wh.x >> 16)
               + bf2f(wh.y & 0xFFFFu) + bf2f(wh.y >> 16);
            s += bf2f(wl.x & 0xFFFFu) + bf2f(wl.x >> 16)
               + bf2f(wl.y & 0xFFFFu) + bf2f(wl.y >> 16);
        }
        float* mp = ws + OFF_MP + (size_t)blockIdx.x * MP_STRIDE;
        mp[4096 + tid] = s;
    }
}

// ---------------------------------------------------------------------------
// k_red: reduce 128 partials per batch -> M, u, v.  grid (17, 2).
// ---------------------------------------------------------------------------
__global__ __launch_bounds__(256) void k_red(float* __restrict__ ws)
{
    const int cell = blockIdx.x * 256 + threadIdx.x;
    const int b    = blockIdx.y;
    if (cell >= MP_STRIDE) return;
    const float* base = ws + OFF_MP + (size_t)(b * 128) * MP_STRIDE + cell;
    float s0 = 0.f, s1 = 0.f, s2 = 0.f, s3 = 0.f;
#pragma unroll 4
    for (int p = 0; p < 128; p += 4) {
        s0 += base[(size_t)(p + 0) * MP_STRIDE];
        s1 += base[(size_t)(p + 1) * MP_STRIDE];
        s2 += base[(size_t)(p + 2) * MP_STRIDE];
        s3 += base[(size_t)(p + 3) * MP_STRIDE];
    }
    float s = (s0 + s1) + (s2 + s3);
    if (cell < 4096)       ws[OFF_M + b * 4096 + cell] = s;
    else if (cell < 4160)  ws[OFF_U + b * 64 + (cell - 4096)] = s;
    else                   ws[OFF_V + b * 64 + (cell - 4160)] = s;
}

// ---------------------------------------------------------------------------
// k_N2: finalize M (bias cross-terms), N2 = M @ WO^T; write N2^T bf16 hi/lo;
// bO2 = bO + b1^T N2.  grid (8, B), 256 thr.
// ---------------------------------------------------------------------------
__global__ __launch_bounds__(256) void k_N2(
    const float* __restrict__ b1, const float* __restrict__ b2,
    const float* __restrict__ b3, const float* __restrict__ WO,
    const float* __restrict__ bO, float* __restrict__ ws)
{
    const int jb = blockIdx.x;
    const int b  = blockIdx.y;

    __shared__ float Ms[64][68];
    __shared__ float WOs[64][68];
    __shared__ float us[64], vs[64];
    __shared__ float bo2s[64];

    const int tid = threadIdx.x;
    const float* M = ws + OFF_M + b * 4096;
#pragma unroll
    for (int t = 0; t < 16; ++t) {
        int e = t * 256 + tid;
        Ms[e >> 6][e & 63] = M[e];
    }
    if (tid < 64)       us[tid]      = ws[OFF_U + b * 64 + tid];
    else if (tid < 128) vs[tid - 64] = ws[OFF_V + b * 64 + tid - 64];
    if (tid < 64) bo2s[tid] = 0.f;
    __syncthreads();
#pragma unroll
    for (int t = 0; t < 16; ++t) {
        int e = t * 256 + tid;
        int d2 = e >> 6, d3 = e & 63;
        Ms[d2][d3] += us[d2] * b3[d3] + b2[d2] * vs[d3] + (float)S_LEN * b2[d2] * b3[d3];
    }
    const int j0 = jb * 64;
#pragma unroll
    for (int t = 0; t < 4; ++t) {
        int idx = tid + t * 256;
        int r = idx >> 4, c4 = idx & 15;
        *(float4*)&WOs[r][c4 * 4] = *(const float4*)(WO + (size_t)(j0 + r) * D_DIM + c4 * 4);
    }
    __syncthreads();

    const int tr = tid >> 4, tc = tid & 15;
    float acc[4][4];
#pragma unroll
    for (int i = 0; i < 4; ++i)
#pragma unroll
        for (int j = 0; j < 4; ++j) acc[i][j] = 0.f;
#pragma unroll 8
    for (int d = 0; d < 64; ++d) {
        float av[4], bw[4];
#pragma unroll
        for (int i = 0; i < 4; ++i) av[i] = Ms[tr * 4 + i][d];
#pragma unroll
        for (int j = 0; j < 4; ++j) bw[j] = WOs[tc * 4 + j][d];
#pragma unroll
        for (int i = 0; i < 4; ++i)
#pragma unroll
            for (int j = 0; j < 4; ++j) acc[i][j] += av[i] * bw[j];
    }
    u16* N2THI = (u16*)(ws + OFF_U16) + U_N2THI + b * IN_DIM * D_DIM;
    u16* N2TLO = (u16*)(ws + OFF_U16) + U_N2TLO + b * IN_DIM * D_DIM;
#pragma unroll
    for (int i = 0; i < 4; ++i)
#pragma unroll
        for (int j = 0; j < 4; ++j) {
            const int col = j0 + tc * 4 + j;
            const int d   = tr * 4 + i;
            float val = acc[i][j];
            u16 h = f2bf_rne(val);
            N2THI[col * D_DIM + d] = h;
            N2TLO[col * D_DIM + d] = f2bf_rne(val - bf2f(h));
        }
#pragma unroll
    for (int j = 0; j < 4; ++j) {
        float s = 0.f;
#pragma unroll
        for (int i = 0; i < 4; ++i) s += b1[tr * 4 + i] * acc[i][j];
        atomicAdd(&bo2s[tc * 4 + j], s);
    }
    __syncthreads();
    if (tid < 64)
        ws[OFF_BO2 + b * IN_DIM + j0 + tid] = bO[j0 + tid] + bo2s[tid];
}

// ---------------------------------------------------------------------------
// k_out: out = sigmoid(Y1 @ N2 + bO2), split-bf16 MFMA, no LDS.
// Block 256 = 4 waves; 32 rows/block; wave g -> cols [128g,128g+128). grid 512.
// ---------------------------------------------------------------------------
__global__ __launch_bounds__(256) void k_out(
    const float* __restrict__ ws, float* __restrict__ out)
{
    const int row0 = blockIdx.x * 32;
    const int b    = row0 >> 13;
    const u16* ub    = (const u16*)(ws + OFF_U16);
    const u16* N2THI = ub + U_N2THI + b * IN_DIM * D_DIM;
    const u16* N2TLO = ub + U_N2TLO + b * IN_DIM * D_DIM;
    const u16* Y1HI  = ub + U_Y1HI;
    const u16* Y1LO  = ub + U_Y1LO;

    const int tid  = threadIdx.x;
    const int lane = tid & 63;
    const int g    = tid >> 6;
    const int ln   = lane & 15;
    const int hf   = lane >> 4;

    f4v acc[2][8];
#pragma unroll
    for (int rt = 0; rt < 2; ++rt)
#pragma unroll
        for (int ct = 0; ct < 8; ++ct) acc[rt][ct] = (f4v)0.f;

#pragma unroll
    for (int ks = 0; ks < 2; ++ks) {
        const int kk = ks * 32 + hf * 8;
        s8v ah[2], al[2];
#pragma unroll
        for (int rt = 0; rt < 2; ++rt) {
            const size_t row = row0 + rt * 16 + ln;
            ah[rt] = *(const s8v*)(Y1HI + row * 64 + kk);
            al[rt] = *(const s8v*)(Y1LO + row * 64 + kk);
        }
#pragma unroll
        for (int ct = 0; ct < 8; ++ct) {
            const int col = g * 128 + ct * 16 + ln;
            s8v bh = *(const s8v*)(N2THI + col * 64 + kk);
            s8v bl = *(const s8v*)(N2TLO + col * 64 + kk);
#pragma unroll
            for (int rt = 0; rt < 2; ++rt) {
                acc[rt][ct] = MFMA(ah[rt], bh, acc[rt][ct]);
                acc[rt][ct] = MFMA(ah[rt], bl, acc[rt][ct]);
                acc[rt][ct] = MFMA(al[rt], bh, acc[rt][ct]);
            }
        }
    }

    const float* bO2 = ws + OFF_BO2 + b * IN_DIM;
#pragma unroll
    for (int ct = 0; ct < 8; ++ct) {
        const int col = g * 128 + ct * 16 + ln;
        const float bias = bO2[col];
#pragma unroll
        for (int rt = 0; rt < 2; ++rt) {
            const int rr = row0 + rt * 16 + hf * 4;
            f4v a = acc[rt][ct];
#pragma unroll
            for (int r = 0; r < 4; ++r) {
                float p = a[r] + bias;
                out[(size_t)(rr + r) * IN_DIM + col] =
                    __builtin_amdgcn_rcpf(1.f + __expf(-p));
            }
        }
    }
}

// ---------------------------------------------------------------------------
extern "C" void kernel_launch(void* const* d_in, const int* in_sizes, int n_in,
                              void* d_out, int out_size, void* d_ws, size_t ws_size,
                              hipStream_t stream)
{
    const float* x  = (const float*)d_in[0];
    const float* W1 = (const float*)d_in[1];
    const float* b1 = (const float*)d_in[2];
    const float* W2 = (const float*)d_in[3];
    const float* b2 = (const float*)d_in[4];
    const float* W3 = (const float*)d_in[5];
    const float* b3 = (const float*)d_in[6];
    const float* WO = (const float*)d_in[7];
    const float* bO = (const float*)d_in[8];
    float* out = (float*)d_out;
    float* ws  = (float*)d_ws;

    k_split<<<96,              256, 0, stream>>>(W1, W2, W3, ws);
    k_proj <<<256,             256, 0, stream>>>(x, ws);
    k_red  <<<dim3(17, BATCH), 256, 0, stream>>>(ws);
    k_N2   <<<dim3(8, BATCH),  256, 0, stream>>>(b1, b2, b3, WO, bO, ws);
    k_out  <<<512,             256, 0, stream>>>(ws, out);
}

// Round 5
// 58.743 us; speedup vs baseline: 1.8811x; 1.1653x over previous
//
#include <hip/hip_runtime.h>
#include <cstdint>

#define S_LEN  8192
#define IN_DIM 512
#define D_DIM  64
#define BATCH  2
#define ROWS   (BATCH * S_LEN)   // 16384

typedef unsigned short u16;
typedef unsigned int   u32;
typedef __attribute__((ext_vector_type(8))) short          s8v;   // 8 bf16 (4 VGPR)
typedef __attribute__((ext_vector_type(4))) float          f4v;

// ---- ws layout (float offsets) ----
#define MP_STRIDE 4224                         // 4096 M cells + 64 u + 64 v
#define OFF_MP   0                             // [256][4224] fp32 partials
#define OFF_M    1081344                       // [B][4096]
#define OFF_U    1089536                       // [B][64]
#define OFF_V    1089664                       // [B][64]
#define OFF_BO2  1089792                       // [B][512]
#define OFF_U16  1090816                       // u16 region starts here
// u16 offsets within region:
#define U_WHI    0                             // [192][512]
#define U_WLO    98304                         // [192][512]
#define U_N2THI  0                             // [B][512][64] (reuse; W dead)
#define U_N2TLO  65536
#define U_Y1HI   196608                        // [16384][64]
#define U_Y1LO   1245184                       // [16384][64]

__device__ __forceinline__ u16 f2bf_rne(float f) {
    u32 u = __float_as_uint(f);
    return (u16)((u + 0x7fffu + ((u >> 16) & 1u)) >> 16);
}
__device__ __forceinline__ float bf2f(u32 h) {
    return __uint_as_float(h << 16);
}
__device__ __forceinline__ float hi_trunc(float f) {
    return __uint_as_float(__float_as_uint(f) & 0xFFFF0000u);
}
// pack top-16 bits of f0 (low half) and f1 (high half) into one u32
__device__ __forceinline__ u32 packhi2(float f0, float f1) {
    return __builtin_amdgcn_perm(__float_as_uint(f1), __float_as_uint(f0), 0x07060302u);
}
#define MFMA(a, b, c) __builtin_amdgcn_mfma_f32_16x16x32_bf16((a), (b), (c), 0, 0, 0)

// ---------------------------------------------------------------------------
// k_split: W{1,2,3} -> concat bf16 hi/lo [192][512] (RNE, one-time).
// ---------------------------------------------------------------------------
__global__ __launch_bounds__(256) void k_split(
    const float* __restrict__ W1, const float* __restrict__ W2,
    const float* __restrict__ W3, float* __restrict__ ws)
{
    const int gid = blockIdx.x * 256 + threadIdx.x;    // 0..24575
    const int w   = gid >> 13;
    const int off = (gid & 8191) * 4;
    const float* Wsrc = (w == 0) ? W1 : (w == 1) ? W2 : W3;
    float4 v = *(const float4*)(Wsrc + off);
    u16* WHI = (u16*)(ws + OFF_U16) + U_WHI + gid * 4;
    u16* WLO = (u16*)(ws + OFF_U16) + U_WLO + gid * 4;
    ushort4 h, l;
    h.x = f2bf_rne(v.x); h.y = f2bf_rne(v.y); h.z = f2bf_rne(v.z); h.w = f2bf_rne(v.w);
    l.x = f2bf_rne(v.x - bf2f(h.x)); l.y = f2bf_rne(v.y - bf2f(h.y));
    l.z = f2bf_rne(v.z - bf2f(h.z)); l.w = f2bf_rne(v.w - bf2f(h.w));
    *(ushort4*)WHI = h;
    *(ushort4*)WLO = l;
}

// ---------------------------------------------------------------------------
// k_proj: Y[16384][192] = x @ Wcat^T (split-bf16 MFMA, hh+hl+lh), fused with
//   per-block M-partial = Y2_tile^T @ Y3_tile and u/v colsum partials.
// Block 256 thr = 4 waves; BM=64 rows; wave g = cols [48g,48g+48) (R=4,C=3).
// 2-deep x-chunk prefetch (regs), chunk-granular B double-buffer. grid 256.
// ---------------------------------------------------------------------------
__global__ __launch_bounds__(256, 1) void k_proj(
    const float* __restrict__ x, float* __restrict__ ws)
{
    u16* const ub = (u16*)(ws + OFF_U16);
    const u16* WHI = ub + U_WHI;
    const u16* WLO = ub + U_WLO;
    u16* Y1HI = ub + U_Y1HI;
    u16* Y1LO = ub + U_Y1LO;

    // union LDS: main loop uses [0..8192) as swizzled xhi/xlo [64][64];
    // epilogue uses 6 x [64][72] u16 transpose buffers (Y1/Y2/Y3 hi,lo).
    __shared__ u16 lds[6 * 64 * 72];   // 27648 u16 = 54 KB
    u16* xhi = lds;
    u16* xlo = lds + 4096;

    const int tid  = threadIdx.x;
    const int lane = tid & 63;
    const int g    = tid >> 6;        // wave id = colgroup 0..3
    const int ln   = lane & 15;
    const int hf   = lane >> 4;       // 0..3
    const int row0 = blockIdx.x * 64;

    // staging map: thread -> (srow 0..63, sk in {0,16,32,48})
    const int srow = tid >> 2;
    const int sk   = (tid & 3) * 16;
    const float* xsrc = x + (size_t)(row0 + srow) * IN_DIM + sk;

    f4v acc[4][3];
#pragma unroll
    for (int rt = 0; rt < 4; ++rt)
#pragma unroll
        for (int ct = 0; ct < 3; ++ct) acc[rt][ct] = (f4v)0.f;

    const u16* bh = WHI + (size_t)(g * 48 + ln) * IN_DIM;
    const u16* bl = WLO + (size_t)(g * 48 + ln) * IN_DIM;

    // B pipeline: [chunk parity][kstep-in-chunk][ct]
    s8v Bh[2][2][3], Bl[2][2][3];
#pragma unroll
    for (int ks = 0; ks < 2; ++ks)
#pragma unroll
        for (int ct = 0; ct < 3; ++ct) {
            Bh[0][ks][ct] = *(const s8v*)(bh + ct * 8192 + ks * 32 + hf * 8);
            Bl[0][ks][ct] = *(const s8v*)(bl + ct * 8192 + ks * 32 + hf * 8);
        }

    // x pipeline: 2-deep, two register buffers
    float4 pf[2][4];
#pragma unroll
    for (int q = 0; q < 4; ++q) pf[0][q] = *(const float4*)(xsrc + q * 4);
#pragma unroll
    for (int q = 0; q < 4; ++q) pf[1][q] = *(const float4*)(xsrc + 64 + q * 4);

#pragma unroll
    for (int c = 0; c < 8; ++c) {
        const int pb = c & 1;
        // ---- stage chunk c: trunc hi/lo split, XOR-swizzled LDS ----
        {
            float vv[16];
#pragma unroll
            for (int q = 0; q < 4; ++q) {
                vv[q*4+0] = pf[pb][q].x; vv[q*4+1] = pf[pb][q].y;
                vv[q*4+2] = pf[pb][q].z; vv[q*4+3] = pf[pb][q].w;
            }
            const int rbase = srow * 64;
            const int sw = srow & 7;
#pragma unroll
            for (int gg = 0; gg < 2; ++gg) {
                const int e = gg * 8;
                uint4 H, L;
                H.x = packhi2(vv[e+0], vv[e+1]); H.y = packhi2(vv[e+2], vv[e+3]);
                H.z = packhi2(vv[e+4], vv[e+5]); H.w = packhi2(vv[e+6], vv[e+7]);
                float l0 = vv[e+0]-hi_trunc(vv[e+0]), l1 = vv[e+1]-hi_trunc(vv[e+1]);
                float l2 = vv[e+2]-hi_trunc(vv[e+2]), l3 = vv[e+3]-hi_trunc(vv[e+3]);
                float l4 = vv[e+4]-hi_trunc(vv[e+4]), l5 = vv[e+5]-hi_trunc(vv[e+5]);
                float l6 = vv[e+6]-hi_trunc(vv[e+6]), l7 = vv[e+7]-hi_trunc(vv[e+7]);
                L.x = packhi2(l0, l1); L.y = packhi2(l2, l3);
                L.z = packhi2(l4, l5); L.w = packhi2(l6, l7);
                const int slot = ((((sk >> 3) + gg) ^ sw) << 3);
                *(uint4*)(xhi + rbase + slot) = H;
                *(uint4*)(xlo + rbase + slot) = L;
            }
        }
        __syncthreads();
        // ---- issue next loads: x chunk c+2 (2-deep), B chunk c+1 ----
        if (c < 6) {
            const float* nx = xsrc + (c + 2) * 64;
#pragma unroll
            for (int q = 0; q < 4; ++q) pf[pb][q] = *(const float4*)(nx + q * 4);
        }
        if (c < 7) {
            const int t0 = 2 * (c + 1);
#pragma unroll
            for (int ks = 0; ks < 2; ++ks)
#pragma unroll
                for (int ct = 0; ct < 3; ++ct) {
                    Bh[1 - pb][ks][ct] = *(const s8v*)(bh + ct * 8192 + (t0 + ks) * 32 + hf * 8);
                    Bl[1 - pb][ks][ct] = *(const s8v*)(bl + ct * 8192 + (t0 + ks) * 32 + hf * 8);
                }
        }
        // ---- compute the 2 ksteps of chunk c ----
#pragma unroll
        for (int ks = 0; ks < 2; ++ks) {
            const int sb = ks * 4 + hf;
            s8v ah[4], al[4];
#pragma unroll
            for (int rt = 0; rt < 4; ++rt) {
                const int arow = rt * 16 + ln;
                const int slot = ((sb ^ (arow & 7)) << 3);
                ah[rt] = *(const s8v*)(xhi + arow * 64 + slot);
                al[rt] = *(const s8v*)(xlo + arow * 64 + slot);
            }
#pragma unroll
            for (int ct = 0; ct < 3; ++ct)
#pragma unroll
                for (int rt = 0; rt < 4; ++rt) {
                    acc[rt][ct] = MFMA(ah[rt], Bh[pb][ks][ct], acc[rt][ct]);
                    acc[rt][ct] = MFMA(ah[rt], Bl[pb][ks][ct], acc[rt][ct]);
                    acc[rt][ct] = MFMA(al[rt], Bh[pb][ks][ct], acc[rt][ct]);
                }
        }
        __syncthreads();
    }

    // ================= epilogue =================
    // E1: write all acc tiles, trunc hi/lo split, into column-major LDS
    // transpose buffers YT[sel][c][r] (sel 0=Y1,1=Y2,2=Y3), stride 72.
#pragma unroll
    for (int rt = 0; rt < 4; ++rt) {
        const int rr = rt * 16 + hf * 4;
#pragma unroll
        for (int ct = 0; ct < 3; ++ct) {
            const int cg  = g * 48 + ct * 16 + ln;
            const int sel = cg >> 6;
            const int ci  = cg & 63;
            f4v a = acc[rt][ct];
            uint2 H, L;
            H.x = packhi2(a[0], a[1]); H.y = packhi2(a[2], a[3]);
            float l0 = a[0]-hi_trunc(a[0]), l1 = a[1]-hi_trunc(a[1]);
            float l2 = a[2]-hi_trunc(a[2]), l3 = a[3]-hi_trunc(a[3]);
            L.x = packhi2(l0, l1); L.y = packhi2(l2, l3);
            u16* dh = lds + (size_t)(sel * 2 + 0) * 4608 + ci * 72 + rr;
            u16* dl = lds + (size_t)(sel * 2 + 1) * 4608 + ci * 72 + rr;
            *(uint2*)dh = H;
            *(uint2*)dl = L;
        }
    }
    __syncthreads();

    // E3: M-partial = Y2^T @ Y3 over these 64 rows (wave g -> M rows 16g..16g+15)
    {
        const u16* y2h = lds + 2 * 4608;
        const u16* y2l = lds + 3 * 4608;
        const u16* y3h = lds + 4 * 4608;
        const u16* y3l = lds + 5 * 4608;
        f4v macc[4];
#pragma unroll
        for (int mj = 0; mj < 4; ++mj) macc[mj] = (f4v)0.f;
#pragma unroll
        for (int ks = 0; ks < 2; ++ks) {
            const int koff = ks * 32 + hf * 8;
            s8v a2h = *(const s8v*)(y2h + (g * 16 + ln) * 72 + koff);
            s8v a2l = *(const s8v*)(y2l + (g * 16 + ln) * 72 + koff);
#pragma unroll
            for (int mj = 0; mj < 4; ++mj) {
                s8v b3h = *(const s8v*)(y3h + (mj * 16 + ln) * 72 + koff);
                s8v b3l = *(const s8v*)(y3l + (mj * 16 + ln) * 72 + koff);
                macc[mj] = MFMA(a2h, b3h, macc[mj]);
                macc[mj] = MFMA(a2h, b3l, macc[mj]);
                macc[mj] = MFMA(a2l, b3h, macc[mj]);
            }
        }
        float* mp = ws + OFF_MP + (size_t)blockIdx.x * MP_STRIDE;
#pragma unroll
        for (int mj = 0; mj < 4; ++mj)
#pragma unroll
            for (int r = 0; r < 4; ++r)
                mp[(g * 16 + hf * 4 + r) * 64 + mj * 16 + ln] = macc[mj][r];
    }

    // E2: store Y1 (cols 0..63) row-major bf16 hi/lo to global
    {
        const int r = tid >> 2;          // 0..63
        const int q = tid & 3;           // 16-col group
        u16 th[16], tl[16];
#pragma unroll
        for (int j = 0; j < 16; ++j) {
            const int ci = q * 16 + j;
            th[j] = lds[0 * 4608 + ci * 72 + r];
            tl[j] = lds[1 * 4608 + ci * 72 + r];
        }
        uint4 H, L, H2, L2;
        H.x = (u32)th[0] | ((u32)th[1] << 16);  H.y = (u32)th[2] | ((u32)th[3] << 16);
        H.z = (u32)th[4] | ((u32)th[5] << 16);  H.w = (u32)th[6] | ((u32)th[7] << 16);
        H2.x = (u32)th[8] | ((u32)th[9] << 16);  H2.y = (u32)th[10] | ((u32)th[11] << 16);
        H2.z = (u32)th[12] | ((u32)th[13] << 16); H2.w = (u32)th[14] | ((u32)th[15] << 16);
        L.x = (u32)tl[0] | ((u32)tl[1] << 16);  L.y = (u32)tl[2] | ((u32)tl[3] << 16);
        L.z = (u32)tl[4] | ((u32)tl[5] << 16);  L.w = (u32)tl[6] | ((u32)tl[7] << 16);
        L2.x = (u32)tl[8] | ((u32)tl[9] << 16);  L2.y = (u32)tl[10] | ((u32)tl[11] << 16);
        L2.z = (u32)tl[12] | ((u32)tl[13] << 16); L2.w = (u32)tl[14] | ((u32)tl[15] << 16);
        u16* dsth = Y1HI + (size_t)(row0 + r) * 64 + q * 16;
        u16* dstl = Y1LO + (size_t)(row0 + r) * 64 + q * 16;
        *(uint4*)(dsth)     = H;  *(uint4*)(dsth + 8) = H2;
        *(uint4*)(dstl)     = L;  *(uint4*)(dstl + 8) = L2;
    }

    // E5: u/v colsum partials (threads 0..127)
    if (tid < 128) {
        const int c = tid & 63;
        const u16* ph = lds + (size_t)((tid < 64) ? 2 : 4) * 4608 + c * 72;
        const u16* pl = lds + (size_t)((tid < 64) ? 3 : 5) * 4608 + c * 72;
        float s = 0.f;
#pragma unroll
        for (int q = 0; q < 16; ++q) {
            uint2 wh = *(const uint2*)(ph + q * 4);
            uint2 wl = *(const uint2*)(pl + q * 4);
            s += bf2f(wh.x & 0xFFFFu) + bf2f(wh.x >> 16)
               + bf2f(wh.y & 0xFFFFu) + bf2f(wh.y >> 16);
            s += bf2f(wl.x & 0xFFFFu) + bf2f(wl.x >> 16)
               + bf2f(wl.y & 0xFFFFu) + bf2f(wl.y >> 16);
        }
        float* mp = ws + OFF_MP + (size_t)blockIdx.x * MP_STRIDE;
        mp[4096 + tid] = s;
    }
}

// ---------------------------------------------------------------------------
// k_red: reduce 128 partials per batch -> M, u, v.  2 threads/cell + shuffle.
// grid (33, 2) x 256.
// ---------------------------------------------------------------------------
__global__ __launch_bounds__(256) void k_red(float* __restrict__ ws)
{
    const int gid  = blockIdx.x * 256 + threadIdx.x;   // 0..8447
    const int b    = blockIdx.y;
    const int cell = gid >> 1;
    const int half = gid & 1;
    if (cell >= MP_STRIDE) return;
    const float* base = ws + OFF_MP + (size_t)(b * 128 + half * 64) * MP_STRIDE + cell;
    float s0 = 0.f, s1 = 0.f, s2 = 0.f, s3 = 0.f;
#pragma unroll 4
    for (int p = 0; p < 64; p += 4) {
        s0 += base[(size_t)(p + 0) * MP_STRIDE];
        s1 += base[(size_t)(p + 1) * MP_STRIDE];
        s2 += base[(size_t)(p + 2) * MP_STRIDE];
        s3 += base[(size_t)(p + 3) * MP_STRIDE];
    }
    float s = (s0 + s1) + (s2 + s3);
    s += __shfl_xor(s, 1);
    if (half == 0) {
        if (cell < 4096)       ws[OFF_M + b * 4096 + cell] = s;
        else if (cell < 4160)  ws[OFF_U + b * 64 + (cell - 4096)] = s;
        else                   ws[OFF_V + b * 64 + (cell - 4160)] = s;
    }
}

// ---------------------------------------------------------------------------
// k_N2: finalize M (bias cross-terms), N2 = M @ WO^T; write N2^T bf16 hi/lo;
// bO2 = bO + b1^T N2.  grid (8, B), 256 thr.
// ---------------------------------------------------------------------------
__global__ __launch_bounds__(256) void k_N2(
    const float* __restrict__ b1, const float* __restrict__ b2,
    const float* __restrict__ b3, const float* __restrict__ WO,
    const float* __restrict__ bO, float* __restrict__ ws)
{
    const int jb = blockIdx.x;
    const int b  = blockIdx.y;

    __shared__ float Ms[64][68];
    __shared__ float WOs[64][68];
    __shared__ float us[64], vs[64];
    __shared__ float bo2s[64];

    const int tid = threadIdx.x;
    const float* M = ws + OFF_M + b * 4096;
#pragma unroll
    for (int t = 0; t < 16; ++t) {
        int e = t * 256 + tid;
        Ms[e >> 6][e & 63] = M[e];
    }
    if (tid < 64)       us[tid]      = ws[OFF_U + b * 64 + tid];
    else if (tid < 128) vs[tid - 64] = ws[OFF_V + b * 64 + tid - 64];
    if (tid < 64) bo2s[tid] = 0.f;
    __syncthreads();
#pragma unroll
    for (int t = 0; t < 16; ++t) {
        int e = t * 256 + tid;
        int d2 = e >> 6, d3 = e & 63;
        Ms[d2][d3] += us[d2] * b3[d3] + b2[d2] * vs[d3] + (float)S_LEN * b2[d2] * b3[d3];
    }
    const int j0 = jb * 64;
#pragma unroll
    for (int t = 0; t < 4; ++t) {
        int idx = tid + t * 256;
        int r = idx >> 4, c4 = idx & 15;
        *(float4*)&WOs[r][c4 * 4] = *(const float4*)(WO + (size_t)(j0 + r) * D_DIM + c4 * 4);
    }
    __syncthreads();

    const int tr = tid >> 4, tc = tid & 15;
    float acc[4][4];
#pragma unroll
    for (int i = 0; i < 4; ++i)
#pragma unroll
        for (int j = 0; j < 4; ++j) acc[i][j] = 0.f;
#pragma unroll 8
    for (int d = 0; d < 64; ++d) {
        float av[4], bw[4];
#pragma unroll
        for (int i = 0; i < 4; ++i) av[i] = Ms[tr * 4 + i][d];
#pragma unroll
        for (int j = 0; j < 4; ++j) bw[j] = WOs[tc * 4 + j][d];
#pragma unroll
        for (int i = 0; i < 4; ++i)
#pragma unroll
            for (int j = 0; j < 4; ++j) acc[i][j] += av[i] * bw[j];
    }
    u16* N2THI = (u16*)(ws + OFF_U16) + U_N2THI + b * IN_DIM * D_DIM;
    u16* N2TLO = (u16*)(ws + OFF_U16) + U_N2TLO + b * IN_DIM * D_DIM;
#pragma unroll
    for (int i = 0; i < 4; ++i)
#pragma unroll
        for (int j = 0; j < 4; ++j) {
            const int col = j0 + tc * 4 + j;
            const int d   = tr * 4 + i;
            float val = acc[i][j];
            u16 h = f2bf_rne(val);
            N2THI[col * D_DIM + d] = h;
            N2TLO[col * D_DIM + d] = f2bf_rne(val - bf2f(h));
        }
#pragma unroll
    for (int j = 0; j < 4; ++j) {
        float s = 0.f;
#pragma unroll
        for (int i = 0; i < 4; ++i) s += b1[tr * 4 + i] * acc[i][j];
        atomicAdd(&bo2s[tc * 4 + j], s);
    }
    __syncthreads();
    if (tid < 64)
        ws[OFF_BO2 + b * IN_DIM + j0 + tid] = bO[j0 + tid] + bo2s[tid];
}

// ---------------------------------------------------------------------------
// k_out: out = sigmoid(Y1 @ N2 + bO2), split-bf16 MFMA, no LDS.
// Block 256 = 4 waves; 32 rows/block; wave g -> cols [128g,128g+128). grid 512.
// ---------------------------------------------------------------------------
__global__ __launch_bounds__(256) void k_out(
    const float* __restrict__ ws, float* __restrict__ out)
{
    const int row0 = blockIdx.x * 32;
    const int b    = row0 >> 13;
    const u16* ub    = (const u16*)(ws + OFF_U16);
    const u16* N2THI = ub + U_N2THI + b * IN_DIM * D_DIM;
    const u16* N2TLO = ub + U_N2TLO + b * IN_DIM * D_DIM;
    const u16* Y1HI  = ub + U_Y1HI;
    const u16* Y1LO  = ub + U_Y1LO;

    const int tid  = threadIdx.x;
    const int lane = tid & 63;
    const int g    = tid >> 6;
    const int ln   = lane & 15;
    const int hf   = lane >> 4;

    f4v acc[2][8];
#pragma unroll
    for (int rt = 0; rt < 2; ++rt)
#pragma unroll
        for (int ct = 0; ct < 8; ++ct) acc[rt][ct] = (f4v)0.f;

#pragma unroll
    for (int ks = 0; ks < 2; ++ks) {
        const int kk = ks * 32 + hf * 8;
        s8v ah[2], al[2];
#pragma unroll
        for (int rt = 0; rt < 2; ++rt) {
            const size_t row = row0 + rt * 16 + ln;
            ah[rt] = *(const s8v*)(Y1HI + row * 64 + kk);
            al[rt] = *(const s8v*)(Y1LO + row * 64 + kk);
        }
#pragma unroll
        for (int ct = 0; ct < 8; ++ct) {
            const int col = g * 128 + ct * 16 + ln;
            s8v bh = *(const s8v*)(N2THI + col * 64 + kk);
            s8v bl = *(const s8v*)(N2TLO + col * 64 + kk);
#pragma unroll
            for (int rt = 0; rt < 2; ++rt) {
                acc[rt][ct] = MFMA(ah[rt], bh, acc[rt][ct]);
                acc[rt][ct] = MFMA(ah[rt], bl, acc[rt][ct]);
                acc[rt][ct] = MFMA(al[rt], bh, acc[rt][ct]);
            }
        }
    }

    const float* bO2 = ws + OFF_BO2 + b * IN_DIM;
#pragma unroll
    for (int ct = 0; ct < 8; ++ct) {
        const int col = g * 128 + ct * 16 + ln;
        const float bias = bO2[col];
#pragma unroll
        for (int rt = 0; rt < 2; ++rt) {
            const int rr = row0 + rt * 16 + hf * 4;
            f4v a = acc[rt][ct];
#pragma unroll
            for (int r = 0; r < 4; ++r) {
                float p = a[r] + bias;
                out[(size_t)(rr + r) * IN_DIM + col] =
                    __builtin_amdgcn_rcpf(1.f + __expf(-p));
            }
        }
    }
}

// ---------------------------------------------------------------------------
extern "C" void kernel_launch(void* const* d_in, const int* in_sizes, int n_in,
                              void* d_out, int out_size, void* d_ws, size_t ws_size,
                              hipStream_t stream)
{
    const float* x  = (const float*)d_in[0];
    const float* W1 = (const float*)d_in[1];
    const float* b1 = (const float*)d_in[2];
    const float* W2 = (const float*)d_in[3];
    const float* b2 = (const float*)d_in[4];
    const float* W3 = (const float*)d_in[5];
    const float* b3 = (const float*)d_in[6];
    const float* WO = (const float*)d_in[7];
    const float* bO = (const float*)d_in[8];
    float* out = (float*)d_out;
    float* ws  = (float*)d_ws;

    k_split<<<96,              256, 0, stream>>>(W1, W2, W3, ws);
    k_proj <<<256,             256, 0, stream>>>(x, ws);
    k_red  <<<dim3(33, BATCH), 256, 0, stream>>>(ws);
    k_N2   <<<dim3(8, BATCH),  256, 0, stream>>>(b1, b2, b3, WO, bO, ws);
    k_out  <<<512,             256, 0, stream>>>(ws, out);
}

// Round 6
// 57.262 us; speedup vs baseline: 1.9297x; 1.0259x over previous
//
#include <hip/hip_runtime.h>
#include <cstdint>

#define S_LEN  8192
#define IN_DIM 512
#define D_DIM  64
#define BATCH  2
#define ROWS   (BATCH * S_LEN)   // 16384

typedef unsigned short u16;
typedef unsigned int   u32;
typedef __attribute__((ext_vector_type(8))) short          s8v;   // 8 bf16 (4 VGPR)
typedef __attribute__((ext_vector_type(4))) float          f4v;

// ---- ws layout (float offsets) ----
#define MP_STRIDE 4224                         // 4096 M cells + 64 u + 64 v
#define OFF_MP   0                             // [256][4224] fp32 partials
#define OFF_M    1081344                       // [B][4096]
#define OFF_U    1089536                       // [B][64]
#define OFF_V    1089664                       // [B][64]
#define OFF_BO2  1089792                       // [B][512]
#define OFF_U16  1090816                       // u16 region starts here
// u16 offsets within region:
#define U_WHI    0                             // [192][512]
#define U_WLO    98304                         // [192][512]
#define U_N2THI  0                             // [B][512][64] (reuse; W dead)
#define U_N2TLO  65536
#define U_Y1HI   196608                        // [16384][64]
#define U_Y1LO   1245184                       // [16384][64]

__device__ __forceinline__ u16 f2bf_rne(float f) {
    u32 u = __float_as_uint(f);
    return (u16)((u + 0x7fffu + ((u >> 16) & 1u)) >> 16);
}
__device__ __forceinline__ float bf2f(u32 h) {
    return __uint_as_float(h << 16);
}
__device__ __forceinline__ float hi_trunc(float f) {
    return __uint_as_float(__float_as_uint(f) & 0xFFFF0000u);
}
// pack top-16 bits of f0 (low half) and f1 (high half) into one u32
__device__ __forceinline__ u32 packhi2(float f0, float f1) {
    return __builtin_amdgcn_perm(__float_as_uint(f1), __float_as_uint(f0), 0x07060302u);
}
#define MFMA(a, b, c) __builtin_amdgcn_mfma_f32_16x16x32_bf16((a), (b), (c), 0, 0, 0)

// ---------------------------------------------------------------------------
// k_split: W{1,2,3} -> concat bf16 hi/lo [192][512] (RNE, one-time).
// ---------------------------------------------------------------------------
__global__ __launch_bounds__(256) void k_split(
    const float* __restrict__ W1, const float* __restrict__ W2,
    const float* __restrict__ W3, float* __restrict__ ws)
{
    const int gid = blockIdx.x * 256 + threadIdx.x;    // 0..24575
    const int w   = gid >> 13;
    const int off = (gid & 8191) * 4;
    const float* Wsrc = (w == 0) ? W1 : (w == 1) ? W2 : W3;
    float4 v = *(const float4*)(Wsrc + off);
    u16* WHI = (u16*)(ws + OFF_U16) + U_WHI + gid * 4;
    u16* WLO = (u16*)(ws + OFF_U16) + U_WLO + gid * 4;
    ushort4 h, l;
    h.x = f2bf_rne(v.x); h.y = f2bf_rne(v.y); h.z = f2bf_rne(v.z); h.w = f2bf_rne(v.w);
    l.x = f2bf_rne(v.x - bf2f(h.x)); l.y = f2bf_rne(v.y - bf2f(h.y));
    l.z = f2bf_rne(v.z - bf2f(h.z)); l.w = f2bf_rne(v.w - bf2f(h.w));
    *(ushort4*)WHI = h;
    *(ushort4*)WLO = l;
}

// ---------------------------------------------------------------------------
// k_proj: Y[16384][192] = x @ Wcat^T (split-bf16 MFMA, hh+hl+lh), fused with
//   per-block M-partial = Y2_tile^T @ Y3_tile and u/v colsum partials.
// Block 256 thr = 4 waves; BM=64 rows; wave g = cols [48g,48g+48) (R=4,C=3).
// 2-deep x-chunk prefetch (regs), chunk-granular B double-buffer. grid 256.
// (verified r5 — unchanged)
// ---------------------------------------------------------------------------
__global__ __launch_bounds__(256, 1) void k_proj(
    const float* __restrict__ x, float* __restrict__ ws)
{
    u16* const ub = (u16*)(ws + OFF_U16);
    const u16* WHI = ub + U_WHI;
    const u16* WLO = ub + U_WLO;
    u16* Y1HI = ub + U_Y1HI;
    u16* Y1LO = ub + U_Y1LO;

    // union LDS: main loop uses [0..8192) as swizzled xhi/xlo [64][64];
    // epilogue uses 6 x [64][72] u16 transpose buffers (Y1/Y2/Y3 hi,lo).
    __shared__ u16 lds[6 * 64 * 72];   // 27648 u16 = 54 KB
    u16* xhi = lds;
    u16* xlo = lds + 4096;

    const int tid  = threadIdx.x;
    const int lane = tid & 63;
    const int g    = tid >> 6;        // wave id = colgroup 0..3
    const int ln   = lane & 15;
    const int hf   = lane >> 4;       // 0..3
    const int row0 = blockIdx.x * 64;

    // staging map: thread -> (srow 0..63, sk in {0,16,32,48})
    const int srow = tid >> 2;
    const int sk   = (tid & 3) * 16;
    const float* xsrc = x + (size_t)(row0 + srow) * IN_DIM + sk;

    f4v acc[4][3];
#pragma unroll
    for (int rt = 0; rt < 4; ++rt)
#pragma unroll
        for (int ct = 0; ct < 3; ++ct) acc[rt][ct] = (f4v)0.f;

    const u16* bh = WHI + (size_t)(g * 48 + ln) * IN_DIM;
    const u16* bl = WLO + (size_t)(g * 48 + ln) * IN_DIM;

    // B pipeline: [chunk parity][kstep-in-chunk][ct]
    s8v Bh[2][2][3], Bl[2][2][3];
#pragma unroll
    for (int ks = 0; ks < 2; ++ks)
#pragma unroll
        for (int ct = 0; ct < 3; ++ct) {
            Bh[0][ks][ct] = *(const s8v*)(bh + ct * 8192 + ks * 32 + hf * 8);
            Bl[0][ks][ct] = *(const s8v*)(bl + ct * 8192 + ks * 32 + hf * 8);
        }

    // x pipeline: 2-deep, two register buffers
    float4 pf[2][4];
#pragma unroll
    for (int q = 0; q < 4; ++q) pf[0][q] = *(const float4*)(xsrc + q * 4);
#pragma unroll
    for (int q = 0; q < 4; ++q) pf[1][q] = *(const float4*)(xsrc + 64 + q * 4);

#pragma unroll
    for (int c = 0; c < 8; ++c) {
        const int pb = c & 1;
        // ---- stage chunk c: trunc hi/lo split, XOR-swizzled LDS ----
        {
            float vv[16];
#pragma unroll
            for (int q = 0; q < 4; ++q) {
                vv[q*4+0] = pf[pb][q].x; vv[q*4+1] = pf[pb][q].y;
                vv[q*4+2] = pf[pb][q].z; vv[q*4+3] = pf[pb][q].w;
            }
            const int rbase = srow * 64;
            const int sw = srow & 7;
#pragma unroll
            for (int gg = 0; gg < 2; ++gg) {
                const int e = gg * 8;
                uint4 H, L;
                H.x = packhi2(vv[e+0], vv[e+1]); H.y = packhi2(vv[e+2], vv[e+3]);
                H.z = packhi2(vv[e+4], vv[e+5]); H.w = packhi2(vv[e+6], vv[e+7]);
                float l0 = vv[e+0]-hi_trunc(vv[e+0]), l1 = vv[e+1]-hi_trunc(vv[e+1]);
                float l2 = vv[e+2]-hi_trunc(vv[e+2]), l3 = vv[e+3]-hi_trunc(vv[e+3]);
                float l4 = vv[e+4]-hi_trunc(vv[e+4]), l5 = vv[e+5]-hi_trunc(vv[e+5]);
                float l6 = vv[e+6]-hi_trunc(vv[e+6]), l7 = vv[e+7]-hi_trunc(vv[e+7]);
                L.x = packhi2(l0, l1); L.y = packhi2(l2, l3);
                L.z = packhi2(l4, l5); L.w = packhi2(l6, l7);
                const int slot = ((((sk >> 3) + gg) ^ sw) << 3);
                *(uint4*)(xhi + rbase + slot) = H;
                *(uint4*)(xlo + rbase + slot) = L;
            }
        }
        __syncthreads();
        // ---- issue next loads: x chunk c+2 (2-deep), B chunk c+1 ----
        if (c < 6) {
            const float* nx = xsrc + (c + 2) * 64;
#pragma unroll
            for (int q = 0; q < 4; ++q) pf[pb][q] = *(const float4*)(nx + q * 4);
        }
        if (c < 7) {
            const int t0 = 2 * (c + 1);
#pragma unroll
            for (int ks = 0; ks < 2; ++ks)
#pragma unroll
                for (int ct = 0; ct < 3; ++ct) {
                    Bh[1 - pb][ks][ct] = *(const s8v*)(bh + ct * 8192 + (t0 + ks) * 32 + hf * 8);
                    Bl[1 - pb][ks][ct] = *(const s8v*)(bl + ct * 8192 + (t0 + ks) * 32 + hf * 8);
                }
        }
        // ---- compute the 2 ksteps of chunk c ----
#pragma unroll
        for (int ks = 0; ks < 2; ++ks) {
            const int sb = ks * 4 + hf;
            s8v ah[4], al[4];
#pragma unroll
            for (int rt = 0; rt < 4; ++rt) {
                const int arow = rt * 16 + ln;
                const int slot = ((sb ^ (arow & 7)) << 3);
                ah[rt] = *(const s8v*)(xhi + arow * 64 + slot);
                al[rt] = *(const s8v*)(xlo + arow * 64 + slot);
            }
#pragma unroll
            for (int ct = 0; ct < 3; ++ct)
#pragma unroll
                for (int rt = 0; rt < 4; ++rt) {
                    acc[rt][ct] = MFMA(ah[rt], Bh[pb][ks][ct], acc[rt][ct]);
                    acc[rt][ct] = MFMA(ah[rt], Bl[pb][ks][ct], acc[rt][ct]);
                    acc[rt][ct] = MFMA(al[rt], Bh[pb][ks][ct], acc[rt][ct]);
                }
        }
        __syncthreads();
    }

    // ================= epilogue =================
    // E1: write all acc tiles, trunc hi/lo split, into column-major LDS
    // transpose buffers YT[sel][c][r] (sel 0=Y1,1=Y2,2=Y3), stride 72.
#pragma unroll
    for (int rt = 0; rt < 4; ++rt) {
        const int rr = rt * 16 + hf * 4;
#pragma unroll
        for (int ct = 0; ct < 3; ++ct) {
            const int cg  = g * 48 + ct * 16 + ln;
            const int sel = cg >> 6;
            const int ci  = cg & 63;
            f4v a = acc[rt][ct];
            uint2 H, L;
            H.x = packhi2(a[0], a[1]); H.y = packhi2(a[2], a[3]);
            float l0 = a[0]-hi_trunc(a[0]), l1 = a[1]-hi_trunc(a[1]);
            float l2 = a[2]-hi_trunc(a[2]), l3 = a[3]-hi_trunc(a[3]);
            L.x = packhi2(l0, l1); L.y = packhi2(l2, l3);
            u16* dh = lds + (size_t)(sel * 2 + 0) * 4608 + ci * 72 + rr;
            u16* dl = lds + (size_t)(sel * 2 + 1) * 4608 + ci * 72 + rr;
            *(uint2*)dh = H;
            *(uint2*)dl = L;
        }
    }
    __syncthreads();

    // E3: M-partial = Y2^T @ Y3 over these 64 rows (wave g -> M rows 16g..16g+15)
    {
        const u16* y2h = lds + 2 * 4608;
        const u16* y2l = lds + 3 * 4608;
        const u16* y3h = lds + 4 * 4608;
        const u16* y3l = lds + 5 * 4608;
        f4v macc[4];
#pragma unroll
        for (int mj = 0; mj < 4; ++mj) macc[mj] = (f4v)0.f;
#pragma unroll
        for (int ks = 0; ks < 2; ++ks) {
            const int koff = ks * 32 + hf * 8;
            s8v a2h = *(const s8v*)(y2h + (g * 16 + ln) * 72 + koff);
            s8v a2l = *(const s8v*)(y2l + (g * 16 + ln) * 72 + koff);
#pragma unroll
            for (int mj = 0; mj < 4; ++mj) {
                s8v b3h = *(const s8v*)(y3h + (mj * 16 + ln) * 72 + koff);
                s8v b3l = *(const s8v*)(y3l + (mj * 16 + ln) * 72 + koff);
                macc[mj] = MFMA(a2h, b3h, macc[mj]);
                macc[mj] = MFMA(a2h, b3l, macc[mj]);
                macc[mj] = MFMA(a2l, b3h, macc[mj]);
            }
        }
        float* mp = ws + OFF_MP + (size_t)blockIdx.x * MP_STRIDE;
#pragma unroll
        for (int mj = 0; mj < 4; ++mj)
#pragma unroll
            for (int r = 0; r < 4; ++r)
                mp[(g * 16 + hf * 4 + r) * 64 + mj * 16 + ln] = macc[mj][r];
    }

    // E2: store Y1 (cols 0..63) row-major bf16 hi/lo to global
    {
        const int r = tid >> 2;          // 0..63
        const int q = tid & 3;           // 16-col group
        u16 th[16], tl[16];
#pragma unroll
        for (int j = 0; j < 16; ++j) {
            const int ci = q * 16 + j;
            th[j] = lds[0 * 4608 + ci * 72 + r];
            tl[j] = lds[1 * 4608 + ci * 72 + r];
        }
        uint4 H, L, H2, L2;
        H.x = (u32)th[0] | ((u32)th[1] << 16);  H.y = (u32)th[2] | ((u32)th[3] << 16);
        H.z = (u32)th[4] | ((u32)th[5] << 16);  H.w = (u32)th[6] | ((u32)th[7] << 16);
        H2.x = (u32)th[8] | ((u32)th[9] << 16);  H2.y = (u32)th[10] | ((u32)th[11] << 16);
        H2.z = (u32)th[12] | ((u32)th[13] << 16); H2.w = (u32)th[14] | ((u32)th[15] << 16);
        L.x = (u32)tl[0] | ((u32)tl[1] << 16);  L.y = (u32)tl[2] | ((u32)tl[3] << 16);
        L.z = (u32)tl[4] | ((u32)tl[5] << 16);  L.w = (u32)tl[6] | ((u32)tl[7] << 16);
        L2.x = (u32)tl[8] | ((u32)tl[9] << 16);  L2.y = (u32)tl[10] | ((u32)tl[11] << 16);
        L2.z = (u32)tl[12] | ((u32)tl[13] << 16); L2.w = (u32)tl[14] | ((u32)tl[15] << 16);
        u16* dsth = Y1HI + (size_t)(row0 + r) * 64 + q * 16;
        u16* dstl = Y1LO + (size_t)(row0 + r) * 64 + q * 16;
        *(uint4*)(dsth)     = H;  *(uint4*)(dsth + 8) = H2;
        *(uint4*)(dstl)     = L;  *(uint4*)(dstl + 8) = L2;
    }

    // E5: u/v colsum partials (threads 0..127)
    if (tid < 128) {
        const int c = tid & 63;
        const u16* ph = lds + (size_t)((tid < 64) ? 2 : 4) * 4608 + c * 72;
        const u16* pl = lds + (size_t)((tid < 64) ? 3 : 5) * 4608 + c * 72;
        float s = 0.f;
#pragma unroll
        for (int q = 0; q < 16; ++q) {
            uint2 wh = *(const uint2*)(ph + q * 4);
            uint2 wl = *(const uint2*)(pl + q * 4);
            s += bf2f(wh.x & 0xFFFFu) + bf2f(wh.x >> 16)
               + bf2f(wh.y & 0xFFFFu) + bf2f(wh.y >> 16);
            s += bf2f(wl.x & 0xFFFFu) + bf2f(wl.x >> 16)
               + bf2f(wl.y & 0xFFFFu) + bf2f(wl.y >> 16);
        }
        float* mp = ws + OFF_MP + (size_t)blockIdx.x * MP_STRIDE;
        mp[4096 + tid] = s;
    }
}

// ---------------------------------------------------------------------------
// k_red: reduce 128 partials per batch -> M, u, v.  4 threads/cell, each sums
// 32 partials, 2-step shuffle combine.  grid (66, 2) x 256 (widened from 2-way:
// per-CU partial-read bytes halve -> ~1.3 us).
// ---------------------------------------------------------------------------
__global__ __launch_bounds__(256) void k_red(float* __restrict__ ws)
{
    const int gid  = blockIdx.x * 256 + threadIdx.x;   // 0..16895
    const int b    = blockIdx.y;
    const int cell = gid >> 2;
    const int qtr  = gid & 3;
    if (cell >= MP_STRIDE) return;
    const float* base = ws + OFF_MP + (size_t)(b * 128 + qtr * 32) * MP_STRIDE + cell;
    float s0 = 0.f, s1 = 0.f, s2 = 0.f, s3 = 0.f;
#pragma unroll 4
    for (int p = 0; p < 32; p += 4) {
        s0 += base[(size_t)(p + 0) * MP_STRIDE];
        s1 += base[(size_t)(p + 1) * MP_STRIDE];
        s2 += base[(size_t)(p + 2) * MP_STRIDE];
        s3 += base[(size_t)(p + 3) * MP_STRIDE];
    }
    float s = (s0 + s1) + (s2 + s3);
    s += __shfl_xor(s, 1);
    s += __shfl_xor(s, 2);
    if (qtr == 0) {
        if (cell < 4096)       ws[OFF_M + b * 4096 + cell] = s;
        else if (cell < 4160)  ws[OFF_U + b * 64 + (cell - 4096)] = s;
        else                   ws[OFF_V + b * 64 + (cell - 4160)] = s;
    }
}

// ---------------------------------------------------------------------------
// k_N2: finalize M (bias cross-terms), N2 = M @ WO^T; write N2^T bf16 hi/lo;
// bO2 = bO + b1^T N2.  grid (8, B), 256 thr. (verified r5 — unchanged)
// ---------------------------------------------------------------------------
__global__ __launch_bounds__(256) void k_N2(
    const float* __restrict__ b1, const float* __restrict__ b2,
    const float* __restrict__ b3, const float* __restrict__ WO,
    const float* __restrict__ bO, float* __restrict__ ws)
{
    const int jb = blockIdx.x;
    const int b  = blockIdx.y;

    __shared__ float Ms[64][68];
    __shared__ float WOs[64][68];
    __shared__ float us[64], vs[64];
    __shared__ float bo2s[64];

    const int tid = threadIdx.x;
    const float* M = ws + OFF_M + b * 4096;
#pragma unroll
    for (int t = 0; t < 16; ++t) {
        int e = t * 256 + tid;
        Ms[e >> 6][e & 63] = M[e];
    }
    if (tid < 64)       us[tid]      = ws[OFF_U + b * 64 + tid];
    else if (tid < 128) vs[tid - 64] = ws[OFF_V + b * 64 + tid - 64];
    if (tid < 64) bo2s[tid] = 0.f;
    __syncthreads();
#pragma unroll
    for (int t = 0; t < 16; ++t) {
        int e = t * 256 + tid;
        int d2 = e >> 6, d3 = e & 63;
        Ms[d2][d3] += us[d2] * b3[d3] + b2[d2] * vs[d3] + (float)S_LEN * b2[d2] * b3[d3];
    }
    const int j0 = jb * 64;
#pragma unroll
    for (int t = 0; t < 4; ++t) {
        int idx = tid + t * 256;
        int r = idx >> 4, c4 = idx & 15;
        *(float4*)&WOs[r][c4 * 4] = *(const float4*)(WO + (size_t)(j0 + r) * D_DIM + c4 * 4);
    }
    __syncthreads();

    const int tr = tid >> 4, tc = tid & 15;
    float acc[4][4];
#pragma unroll
    for (int i = 0; i < 4; ++i)
#pragma unroll
        for (int j = 0; j < 4; ++j) acc[i][j] = 0.f;
#pragma unroll 8
    for (int d = 0; d < 64; ++d) {
        float av[4], bw[4];
#pragma unroll
        for (int i = 0; i < 4; ++i) av[i] = Ms[tr * 4 + i][d];
#pragma unroll
        for (int j = 0; j < 4; ++j) bw[j] = WOs[tc * 4 + j][d];
#pragma unroll
        for (int i = 0; i < 4; ++i)
#pragma unroll
            for (int j = 0; j < 4; ++j) acc[i][j] += av[i] * bw[j];
    }
    u16* N2THI = (u16*)(ws + OFF_U16) + U_N2THI + b * IN_DIM * D_DIM;
    u16* N2TLO = (u16*)(ws + OFF_U16) + U_N2TLO + b * IN_DIM * D_DIM;
#pragma unroll
    for (int i = 0; i < 4; ++i)
#pragma unroll
        for (int j = 0; j < 4; ++j) {
            const int col = j0 + tc * 4 + j;
            const int d   = tr * 4 + i;
            float val = acc[i][j];
            u16 h = f2bf_rne(val);
            N2THI[col * D_DIM + d] = h;
            N2TLO[col * D_DIM + d] = f2bf_rne(val - bf2f(h));
        }
#pragma unroll
    for (int j = 0; j < 4; ++j) {
        float s = 0.f;
#pragma unroll
        for (int i = 0; i < 4; ++i) s += b1[tr * 4 + i] * acc[i][j];
        atomicAdd(&bo2s[tc * 4 + j], s);
    }
    __syncthreads();
    if (tid < 64)
        ws[OFF_BO2 + b * IN_DIM + j0 + tid] = bO[j0 + tid] + bo2s[tid];
}

// ---------------------------------------------------------------------------
// k_out: out = sigmoid(Y1 @ N2 + bO2), split-bf16 MFMA, no LDS.
// Block 256 = 4 waves; 32 rows/block; wave g -> cols [128g,128g+128). grid 512.
// (verified r5 — unchanged)
// ---------------------------------------------------------------------------
__global__ __launch_bounds__(256) void k_out(
    const float* __restrict__ ws, float* __restrict__ out)
{
    const int row0 = blockIdx.x * 32;
    const int b    = row0 >> 13;
    const u16* ub    = (const u16*)(ws + OFF_U16);
    const u16* N2THI = ub + U_N2THI + b * IN_DIM * D_DIM;
    const u16* N2TLO = ub + U_N2TLO + b * IN_DIM * D_DIM;
    const u16* Y1HI  = ub + U_Y1HI;
    const u16* Y1LO  = ub + U_Y1LO;

    const int tid  = threadIdx.x;
    const int lane = tid & 63;
    const int g    = tid >> 6;
    const int ln   = lane & 15;
    const int hf   = lane >> 4;

    f4v acc[2][8];
#pragma unroll
    for (int rt = 0; rt < 2; ++rt)
#pragma unroll
        for (int ct = 0; ct < 8; ++ct) acc[rt][ct] = (f4v)0.f;

#pragma unroll
    for (int ks = 0; ks < 2; ++ks) {
        const int kk = ks * 32 + hf * 8;
        s8v ah[2], al[2];
#pragma unroll
        for (int rt = 0; rt < 2; ++rt) {
            const size_t row = row0 + rt * 16 + ln;
            ah[rt] = *(const s8v*)(Y1HI + row * 64 + kk);
            al[rt] = *(const s8v*)(Y1LO + row * 64 + kk);
        }
#pragma unroll
        for (int ct = 0; ct < 8; ++ct) {
            const int col = g * 128 + ct * 16 + ln;
            s8v bh = *(const s8v*)(N2THI + col * 64 + kk);
            s8v bl = *(const s8v*)(N2TLO + col * 64 + kk);
#pragma unroll
            for (int rt = 0; rt < 2; ++rt) {
                acc[rt][ct] = MFMA(ah[rt], bh, acc[rt][ct]);
                acc[rt][ct] = MFMA(ah[rt], bl, acc[rt][ct]);
                acc[rt][ct] = MFMA(al[rt], bh, acc[rt][ct]);
            }
        }
    }

    const float* bO2 = ws + OFF_BO2 + b * IN_DIM;
#pragma unroll
    for (int ct = 0; ct < 8; ++ct) {
        const int col = g * 128 + ct * 16 + ln;
        const float bias = bO2[col];
#pragma unroll
        for (int rt = 0; rt < 2; ++rt) {
            const int rr = row0 + rt * 16 + hf * 4;
            f4v a = acc[rt][ct];
#pragma unroll
            for (int r = 0; r < 4; ++r) {
                float p = a[r] + bias;
                out[(size_t)(rr + r) * IN_DIM + col] =
                    __builtin_amdgcn_rcpf(1.f + __expf(-p));
            }
        }
    }
}

// ---------------------------------------------------------------------------
extern "C" void kernel_launch(void* const* d_in, const int* in_sizes, int n_in,
                              void* d_out, int out_size, void* d_ws, size_t ws_size,
                              hipStream_t stream)
{
    const float* x  = (const float*)d_in[0];
    const float* W1 = (const float*)d_in[1];
    const float* b1 = (const float*)d_in[2];
    const float* W2 = (const float*)d_in[3];
    const float* b2 = (const float*)d_in[4];
    const float* W3 = (const float*)d_in[5];
    const float* b3 = (const float*)d_in[6];
    const float* WO = (const float*)d_in[7];
    const float* bO = (const float*)d_in[8];
    float* out = (float*)d_out;
    float* ws  = (float*)d_ws;

    k_split<<<96,              256, 0, stream>>>(W1, W2, W3, ws);
    k_proj <<<256,             256, 0, stream>>>(x, ws);
    k_red  <<<dim3(66, BATCH), 256, 0, stream>>>(ws);
    k_N2   <<<dim3(8, BATCH),  256, 0, stream>>>(b1, b2, b3, WO, bO, ws);
    k_out  <<<512,             256, 0, stream>>>(ws, out);
}